// Round 3
// baseline (294.056 us; speedup 1.0000x reference)
//
#include <hip/hip_runtime.h>

typedef unsigned short u16;
typedef unsigned char  u8;
typedef unsigned long long u64;
typedef __attribute__((ext_vector_type(8))) short bf16x8;   // 8 bf16 in 4 VGPRs
typedef __attribute__((ext_vector_type(4))) float f32x4;

constexpr int B_  = 2;
constexpr int S_  = 2048;
constexpr int D_  = 1024;
constexpr int H_  = 16;
constexpr int DK_ = 64;
constexpr int NROW = B_ * S_;                           // 4096
constexpr size_t QSZ  = (size_t)B_ * H_ * S_ * DK_;     // 4194304 elems per buffer
constexpr size_t XBSZ = (size_t)NROW * D_;              // 4194304 (one X matrix)
constexpr size_t WBSZ = (size_t)D_ * D_;                // 1048576 (one W matrix)
constexpr size_t MSZ  = (size_t)B_ * S_ * S_;           // 8388608 mask elems
constexpr size_t MPKB = MSZ / 8;                        // 1 MiB packed mask bytes

__device__ __forceinline__ u16 f2bf(float f) {
    union { float f; unsigned u; } c; c.f = f;
    unsigned r = c.u + 0x7fffu + ((c.u >> 16) & 1u);    // RNE
    return (u16)(r >> 16);
}
__device__ __forceinline__ unsigned pack2(float a, float b) {
    return (unsigned)f2bf(a) | ((unsigned)f2bf(b) << 16);
}
// HW packed f32->bf16 RNE: dst.lo = bf16(a), dst.hi = bf16(b). Bit-identical
// to f2bf for finite values (exp() outputs are finite positive).
__device__ __forceinline__ unsigned cvt_pk_bf16(float a, float b) {
    unsigned r;
    asm("v_cvt_pk_bf16_f32 %0, %1, %2" : "=v"(r) : "v"(a), "v"(b));
    return r;
}

// async global->LDS, 16B per lane; lds ptr must be wave-uniform base
__device__ __forceinline__ void gl_lds16(const u16* g, u16* l) {
    __builtin_amdgcn_global_load_lds(
        (const __attribute__((address_space(1))) void*)g,
        (__attribute__((address_space(3))) void*)l, 16, 0, 0);
}

// ---------------------------------------------------------------------------
// cvt7m — UNCHANGED from R11. fp32 -> bf16 RNE of X/W + mask bit-pack.
// ---------------------------------------------------------------------------
__global__ __launch_bounds__(256)
void cvt7m(const float* __restrict__ s0, const float* __restrict__ s1,
           const float* __restrict__ s2, const float* __restrict__ s3,
           const float* __restrict__ s4, const float* __restrict__ s5,
           const float* __restrict__ s6, const int* __restrict__ mk,
           u16* __restrict__ d0, u16* __restrict__ d1, u16* __restrict__ d2,
           u16* __restrict__ d3, u16* __restrict__ d4, u16* __restrict__ d5,
           u16* __restrict__ d6, u8* __restrict__ mp)
{
    constexpr size_t XT = 3 * XBSZ;                            // 12582912
    constexpr int NCF = (int)((3 * XBSZ + 4 * WBSZ) / 2048);   // 8192
    constexpr int NCM = (int)(MSZ / 2048);                     // 4096

    for (int c = blockIdx.x; c < NCF + NCM; c += gridDim.x) {
        if (c < NCF) {
            const size_t base = (size_t)c * 2048;
            const float* s; u16* d; size_t off;
            if (base < XT) {
                const int a = (int)(base >> 22);
                off = base & (XBSZ - 1);
                s = (a == 0) ? s0 : (a == 1) ? s1 : s2;
                d = (a == 0) ? d0 : (a == 1) ? d1 : d2;
            } else {
                const size_t r = base - XT;
                const int a = (int)(r >> 20);
                off = r & (WBSZ - 1);
                s = (a == 0) ? s3 : (a == 1) ? s4 : (a == 2) ? s5 : s6;
                d = (a == 0) ? d3 : (a == 1) ? d4 : (a == 2) ? d5 : d6;
            }
            const size_t e = off + (size_t)threadIdx.x * 8;
            const float4 x0 = *(const float4*)(s + e);
            const float4 x1 = *(const float4*)(s + e + 4);
            uint4 p;
            p.x = pack2(x0.x, x0.y); p.y = pack2(x0.z, x0.w);
            p.z = pack2(x1.x, x1.y); p.w = pack2(x1.z, x1.w);
            *(uint4*)(d + e) = p;
        } else {
            const size_t e = (size_t)(c - NCF) * 2048 + (size_t)threadIdx.x * 8;
            const int4 x0 = *(const int4*)(mk + e);
            const int4 x1 = *(const int4*)(mk + e + 4);
            unsigned bv = (unsigned)(x0.x != 0)        | ((unsigned)(x0.y != 0) << 1)
                        | ((unsigned)(x0.z != 0) << 2) | ((unsigned)(x0.w != 0) << 3)
                        | ((unsigned)(x1.x != 0) << 4) | ((unsigned)(x1.y != 0) << 5)
                        | ((unsigned)(x1.z != 0) << 6) | ((unsigned)(x1.w != 0) << 7);
            mp[e >> 3] = (u8)bv;
        }
    }
}

// ---------------------------------------------------------------------------
// qkv_gemm — UNCHANGED from R10.
// ---------------------------------------------------------------------------
__global__ __launch_bounds__(256, 3)
void qkv_gemm(const u16* __restrict__ Xq, const u16* __restrict__ Xk,
              const u16* __restrict__ Xv,
              const u16* __restrict__ Wq, const u16* __restrict__ Wk,
              const u16* __restrict__ Wv,
              u16* __restrict__ Yq, u16* __restrict__ Yk, u16* __restrict__ Yv)
{
    __shared__ u16 As[128 * 32];
    __shared__ u16 Bs[128 * 32];

    const int z = blockIdx.z;
    const u16* X = (z == 0) ? Xq : (z == 1) ? Xk : Xv;
    const u16* W = (z == 0) ? Wq : (z == 1) ? Wk : Wv;
    u16*       Y = (z == 0) ? Yq : (z == 1) ? Yk : Yv;
    const float osc = (z == 0) ? 0.125f : 1.0f;

    const int tid  = threadIdx.x;
    const int lane = tid & 63;
    const int w    = tid >> 6;
    const int quad = lane >> 4;
    const int lq   = lane & 15;
    const int wm   = (w & 1) << 6;
    const int wn   = (w >> 1) << 6;

    const int m0 = blockIdx.x << 7;
    const int n0 = blockIdx.y << 7;

    const int srow = tid >> 2;
    const int scol = (tid & 3) << 3;
    const u16* ga0 = X + (size_t)(m0 + srow) * D_ + scol;
    const u16* ga1 = ga0 + (size_t)64 * D_;
    const u16* gb0 = W + (size_t)(n0 + srow) * D_ + scol;
    const u16* gb1 = gb0 + (size_t)64 * D_;

    u16* la0 = As + (size_t)w * 512;
    u16* la1 = As + 2048 + (size_t)w * 512;
    u16* lb0 = Bs + (size_t)w * 512;
    u16* lb1 = Bs + 2048 + (size_t)w * 512;

    f32x4 acc[4][4];
#pragma unroll
    for (int i = 0; i < 4; ++i)
#pragma unroll
        for (int j = 0; j < 4; ++j) acc[i][j] = (f32x4){0.f, 0.f, 0.f, 0.f};

    for (int kt = 0; kt < D_; kt += 32) {
        __syncthreads();
        gl_lds16(ga0 + kt, la0);
        gl_lds16(ga1 + kt, la1);
        gl_lds16(gb0 + kt, lb0);
        gl_lds16(gb1 + kt, lb1);
        __syncthreads();

        bf16x8 af[4], bf[4];
#pragma unroll
        for (int t = 0; t < 4; ++t) {
            af[t] = *(const bf16x8*)&As[(size_t)(wm + (t << 4) + lq) * 32 + (quad << 3)];
            bf[t] = *(const bf16x8*)&Bs[(size_t)(wn + (t << 4) + lq) * 32 + (quad << 3)];
        }
#pragma unroll
        for (int i = 0; i < 4; ++i)
#pragma unroll
            for (int j = 0; j < 4; ++j)
                acc[i][j] = __builtin_amdgcn_mfma_f32_16x16x32_bf16(
                    af[i], bf[j], acc[i][j], 0, 0, 0);
    }

#pragma unroll
    for (int i = 0; i < 4; ++i)
#pragma unroll
        for (int j = 0; j < 4; ++j)
#pragma unroll
            for (int r = 0; r < 4; ++r) {
                const int grow = m0 + wm + (i << 4) + (quad << 2) + r;
                const int of   = n0 + wn + (j << 4) + lq;
                const int b = grow >> 11, s = grow & (S_ - 1);
                const int h = of >> 6,    dk = of & 63;
                Y[(((size_t)(b * H_ + h)) * S_ + s) * DK_ + dk] =
                    f2bf(acc[i][j][r] * osc);
            }
}

// ---------------------------------------------------------------------------
// out_gemm — UNCHANGED from R10.
// ---------------------------------------------------------------------------
__global__ __launch_bounds__(256, 3)
void out_gemm(const u16* __restrict__ X, const u16* __restrict__ W,
              float* __restrict__ Y)
{
    __shared__ u16 As[128 * 32];
    __shared__ u16 Bs[128 * 32];

    const int tid  = threadIdx.x;
    const int lane = tid & 63;
    const int w    = tid >> 6;
    const int quad = lane >> 4;
    const int lq   = lane & 15;
    const int wm   = (w & 1) << 6;
    const int wn   = (w >> 1) << 6;

    const int m0 = blockIdx.x << 7;
    const int n0 = blockIdx.y << 7;

    const int srow = tid >> 2;
    const int scol = (tid & 3) << 3;
    const u16* ga0 = X + (size_t)(m0 + srow) * D_ + scol;
    const u16* ga1 = ga0 + (size_t)64 * D_;
    const u16* gb0 = W + (size_t)(n0 + srow) * D_ + scol;
    const u16* gb1 = gb0 + (size_t)64 * D_;

    u16* la0 = As + (size_t)w * 512;
    u16* la1 = As + 2048 + (size_t)w * 512;
    u16* lb0 = Bs + (size_t)w * 512;
    u16* lb1 = Bs + 2048 + (size_t)w * 512;

    f32x4 acc[4][4];
#pragma unroll
    for (int i = 0; i < 4; ++i)
#pragma unroll
        for (int j = 0; j < 4; ++j) acc[i][j] = (f32x4){0.f, 0.f, 0.f, 0.f};

    for (int kt = 0; kt < D_; kt += 32) {
        __syncthreads();
        gl_lds16(ga0 + kt, la0);
        gl_lds16(ga1 + kt, la1);
        gl_lds16(gb0 + kt, lb0);
        gl_lds16(gb1 + kt, lb1);
        __syncthreads();

        bf16x8 af[4], bf[4];
#pragma unroll
        for (int t = 0; t < 4; ++t) {
            af[t] = *(const bf16x8*)&As[(size_t)(wm + (t << 4) + lq) * 32 + (quad << 3)];
            bf[t] = *(const bf16x8*)&Bs[(size_t)(wn + (t << 4) + lq) * 32 + (quad << 3)];
        }
#pragma unroll
        for (int i = 0; i < 4; ++i)
#pragma unroll
            for (int j = 0; j < 2 * 2; ++j)
                acc[i][j] = __builtin_amdgcn_mfma_f32_16x16x32_bf16(
                    af[i], bf[j], acc[i][j], 0, 0, 0);
    }

#pragma unroll
    for (int i = 0; i < 4; ++i)
#pragma unroll
        for (int j = 0; j < 4; ++j)
#pragma unroll
            for (int r = 0; r < 4; ++r) {
                const int grow = m0 + wm + (i << 4) + (quad << 2) + r;
                const int gcol = n0 + wn + (j << 4) + lq;
                Y[(size_t)grow * D_ + gcol] = acc[i][j][r];
            }
}

// ---------------------------------------------------------------------------
// attn_mfma6 (R12): in-block K-split. 512 threads / 8 waves; waves 0-3
// process keys [0,1024), waves 4-7 keys [1024,2048) on the same 128-row
// Q-tile, each group with private Ks/Vt/Ps LDS (73.7 KB total, 2 blocks/CU
// -> 16 waves/CU = 4/SIMD, 2x R11). Inner chunk loop identical to R11.
// Q frags loaded directly from global (no Qs stage). Final combine: group 1
// dumps f32 O/lsum partials into dead Ps/Ks LDS; group 0 adds (fp32
// reassociation only) then does the R11 quad-reduce + normalize + store.
// ---------------------------------------------------------------------------
constexpr int AP = 72;

__global__ __launch_bounds__(512, 4)
void attn_mfma6(const u16* __restrict__ qb, const u16* __restrict__ kb,
                const u16* __restrict__ vb, const u8* __restrict__ mpk,
                u16* __restrict__ ctx)
{
    __shared__ __align__(16) u16 Ks[2][64][AP];
    __shared__ __align__(16) u16 Vt[2][64][AP];     // [d][pi(key)]
    __shared__ __align__(16) u16 Ps[2][128][AP];    // [q][pi(key)]

    const int tid  = threadIdx.x;          // 0..511
    const int lane = tid & 63;
    const int w    = tid >> 6;             // 0..7
    const int g    = w >> 2;               // key-half group
    const int wl   = w & 3;                // wave within group
    const int quad = lane >> 4;
    const int lq   = lane & 15;
    const int w32  = wl << 5;              // wave's 32-row base
    const int tg   = tid & 255;            // thread id within group

    const int q0 = blockIdx.x << 7;
    const int h  = blockIdx.y;
    const int b  = blockIdx.z;

    const u16* qbh = qb + (((size_t)b * H_ + h) * S_ + q0) * DK_;
    const u16* kbh = kb + ((size_t)b * H_ + h) * S_ * DK_ + ((size_t)(g << 10)) * DK_;
    const u16* vbh = vb + ((size_t)b * H_ + h) * S_ * DK_ + ((size_t)(g << 10)) * DK_;

    // Q fragments straight from global (one-time, L2-resident)
    bf16x8 aQ[2][2];
#pragma unroll
    for (int i = 0; i < 2; ++i) {
        const size_t qr = (size_t)(w32 + (i << 4) + lq) * DK_;
        aQ[i][0] = *(const bf16x8*)&qbh[qr + (quad << 3)];
        aQ[i][1] = *(const bf16x8*)&qbh[qr + 32 + (quad << 3)];
    }

    f32x4 O[2][4];
    float lsum[2][4];
#pragma unroll
    for (int i = 0; i < 2; ++i)
#pragma unroll
        for (int t = 0; t < 4; ++t) O[i][t] = (f32x4){0.f, 0.f, 0.f, 0.f};
#pragma unroll
    for (int i = 0; i < 2; ++i)
#pragma unroll
        for (int r = 0; r < 4; ++r) lsum[i][r] = 0.f;

    // staging maps (per group: 256 threads)
    const int ksr = tg >> 2, ksc = (tg & 3) << 4;
    const int vkey = tg & 63, vsc = (tg >> 6) << 4;
    const int vpc  = ((vkey & 15) << 2) | (vkey >> 4);   // pi(key)

    uint4 kr0, kr1; ushort4 vr[4];
    {
        kr0 = *(const uint4*)&kbh[(size_t)ksr * DK_ + ksc];
        kr1 = *(const uint4*)&kbh[(size_t)ksr * DK_ + ksc + 8];
#pragma unroll
        for (int u = 0; u < 4; ++u)
            vr[u] = *(const ushort4*)&vbh[(size_t)vkey * DK_ + vsc + (u << 2)];
    }

    const int qrow0 = q0 + w32 + (quad << 2);
    const u8* mrow = mpk + (size_t)b * S_ * (S_ / 8)
                   + (size_t)qrow0 * (S_ / 8) + (g << 7);

    for (int kk = 0; kk < 1024; kk += 64) {
        // packed mask: one u64 (64 key-bits) per q-row handled by this thread
        u64 mw[2][4];
#pragma unroll
        for (int i = 0; i < 2; ++i)
#pragma unroll
            for (int r = 0; r < 4; ++r)
                mw[i][r] = *(const u64*)&mrow[(size_t)((i << 4) + r) * (S_ / 8) + (kk >> 3)];

        __syncthreads();
        {
            *(uint4*)&Ks[g][ksr][ksc]     = kr0;
            *(uint4*)&Ks[g][ksr][ksc + 8] = kr1;
            const u16 vv[16] = {
                vr[0].x, vr[0].y, vr[0].z, vr[0].w,
                vr[1].x, vr[1].y, vr[1].z, vr[1].w,
                vr[2].x, vr[2].y, vr[2].z, vr[2].w,
                vr[3].x, vr[3].y, vr[3].z, vr[3].w };
#pragma unroll
            for (int i = 0; i < 16; ++i)
                Vt[g][vsc + i][vpc] = vv[i];
        }
        __syncthreads();

        if (kk + 64 < 1024) {   // prefetch next chunk of this group's half
            const size_t kb0 = (size_t)(kk + 64 + ksr) * DK_ + ksc;
            kr0 = *(const uint4*)&kbh[kb0];
            kr1 = *(const uint4*)&kbh[kb0 + 8];
            const size_t vb0 = (size_t)(kk + 64 + vkey) * DK_ + vsc;
#pragma unroll
            for (int u = 0; u < 4; ++u)
                vr[u] = *(const ushort4*)&vbh[vb0 + (u << 2)];
        }

        // ---- S = Q K^T ----
        f32x4 st[2][4];
#pragma unroll
        for (int t = 0; t < 4; ++t) {
            const bf16x8 b0 = *(const bf16x8*)&Ks[g][(t << 4) + lq][quad << 3];
            const bf16x8 b1 = *(const bf16x8*)&Ks[g][(t << 4) + lq][32 + (quad << 3)];
#pragma unroll
            for (int i = 0; i < 2; ++i) {
                f32x4 c = {0.f, 0.f, 0.f, 0.f};
                c = __builtin_amdgcn_mfma_f32_16x16x32_bf16(aQ[i][0], b0, c, 0, 0, 0);
                c = __builtin_amdgcn_mfma_f32_16x16x32_bf16(aQ[i][1], b1, c, 0, 0, 0);
                st[i][t] = c;
            }
        }

        // ---- exp (fixed base), masked selects, l partials, P pack ----
#pragma unroll
        for (int i = 0; i < 2; ++i)
#pragma unroll
            for (int r = 0; r < 4; ++r) {
                const unsigned lo = (unsigned)mw[i][r];
                const unsigned hi = (unsigned)(mw[i][r] >> 32);
                float p0 = __expf(st[i][0][r]);
                float p1 = __expf(st[i][1][r]);
                float p2 = __expf(st[i][2][r]);
                float p3 = __expf(st[i][3][r]);
                p0 = ((lo >> lq) & 1u) ? p0 : 1.0f;
                p1 = ((lo >> (lq + 16)) & 1u) ? p1 : 1.0f;
                p2 = ((hi >> lq) & 1u) ? p2 : 1.0f;
                p3 = ((hi >> (lq + 16)) & 1u) ? p3 : 1.0f;
                lsum[i][r] += (p0 + p1) + (p2 + p3);
                uint2 pw;
                pw.x = cvt_pk_bf16(p0, p1);
                pw.y = cvt_pk_bf16(p2, p3);
                *(uint2*)&Ps[g][w32 + (i << 4) + (quad << 2) + r][lq << 2] = pw;
            }

        // ---- O += P V (wave-local Ps rows: DS in-order, no barrier) ----
        bf16x8 aP[2][2];
#pragma unroll
        for (int i = 0; i < 2; ++i) {
            aP[i][0] = *(const bf16x8*)&Ps[g][w32 + (i << 4) + lq][quad << 3];
            aP[i][1] = *(const bf16x8*)&Ps[g][w32 + (i << 4) + lq][32 + (quad << 3)];
        }
#pragma unroll
        for (int t = 0; t < 4; ++t) {
            const bf16x8 b0 = *(const bf16x8*)&Vt[g][(t << 4) + lq][quad << 3];
            const bf16x8 b1 = *(const bf16x8*)&Vt[g][(t << 4) + lq][32 + (quad << 3)];
#pragma unroll
            for (int i = 0; i < 2; ++i) {
                O[i][t] = __builtin_amdgcn_mfma_f32_16x16x32_bf16(aP[i][0], b0, O[i][t], 0, 0, 0);
                O[i][t] = __builtin_amdgcn_mfma_f32_16x16x32_bf16(aP[i][1], b1, O[i][t], 0, 0, 0);
            }
        }
    }

    // ---- in-block combine: group 1 -> LDS, group 0 accumulates ----
    __syncthreads();
    float* cbO = (float*)&Ps[0][0][0];   // 256*33*4 = 33792 B <= 36864 B
    float* cbL = (float*)&Ks[0][0][0];   // 256*9*4  =  9216 B <= 18432 B
    if (g == 1) {
        const int t1 = tid - 256;
#pragma unroll
        for (int i = 0; i < 2; ++i)
#pragma unroll
            for (int t = 0; t < 4; ++t)
#pragma unroll
                for (int r = 0; r < 4; ++r)
                    cbO[t1 * 33 + (i << 4) + (t << 2) + r] = O[i][t][r];
#pragma unroll
        for (int i = 0; i < 2; ++i)
#pragma unroll
            for (int r = 0; r < 4; ++r)
                cbL[t1 * 9 + (i << 2) + r] = lsum[i][r];
    }
    __syncthreads();
    if (g == 1) return;

#pragma unroll
    for (int i = 0; i < 2; ++i)
#pragma unroll
        for (int t = 0; t < 4; ++t)
#pragma unroll
            for (int r = 0; r < 4; ++r)
                O[i][t][r] += cbO[tid * 33 + (i << 4) + (t << 2) + r];
#pragma unroll
    for (int i = 0; i < 2; ++i)
#pragma unroll
        for (int r = 0; r < 4; ++r)
            lsum[i][r] += cbL[tid * 9 + (i << 2) + r];

    // deferred l reduction (16 lanes of the quad)
#pragma unroll
    for (int i = 0; i < 2; ++i)
#pragma unroll
        for (int r = 0; r < 4; ++r) {
#pragma unroll
            for (int off = 1; off < 16; off <<= 1)
                lsum[i][r] += __shfl_xor(lsum[i][r], off);
            lsum[i][r] = 1.0f / lsum[i][r];
        }

    // epilogue: bf16 ctx [b, s, h*64 + d]
#pragma unroll
    for (int i = 0; i < 2; ++i)
#pragma unroll
        for (int t = 0; t < 4; ++t)
#pragma unroll
            for (int r = 0; r < 4; ++r) {
                const int row = qrow0 + (i << 4) + r;
                ctx[((size_t)b * S_ + row) * D_ + (h << 6) + (t << 4) + lq] =
                    f2bf(O[i][t][r] * lsum[i][r]);
            }
}

// ---------------------------------------------------------------------------
// Workspace layout (u16 units), ~61 MB total (unchanged from R11):
//   [0)              xqb,xkb,xvb : 3*XBSZ  (bf16 X; dead after qkv_gemm)
//   [3*XBSZ)         wqb..wob    : 4*WBSZ  (bf16 W)
//   [3*XBSZ+4*WBSZ)  qw,kw,vw    : 3*QSZ
//   after that       mpk         : MPKB bytes (bit-packed mask)
//   cx aliases xqb (attn writes it after qkv_gemm's last read of xvb).
// ---------------------------------------------------------------------------
extern "C" void kernel_launch(void* const* d_in, const int* in_sizes, int n_in,
                              void* d_out, int out_size, void* d_ws, size_t ws_size,
                              hipStream_t stream)
{
    const float* Q    = (const float*)d_in[0];
    const float* K    = (const float*)d_in[1];
    const float* V    = (const float*)d_in[2];
    const int*   mask = (const int*)d_in[3];
    const float* Wq   = (const float*)d_in[4];
    const float* Wk   = (const float*)d_in[5];
    const float* Wv   = (const float*)d_in[6];
    const float* Wo   = (const float*)d_in[7];
    float* out = (float*)d_out;

    u16* xqb = (u16*)d_ws;
    u16* xkb = xqb + XBSZ;
    u16* xvb = xqb + 2 * XBSZ;
    u16* wqb = xqb + 3 * XBSZ;
    u16* wkb = wqb + WBSZ;
    u16* wvb = wqb + 2 * WBSZ;
    u16* wob = wqb + 3 * WBSZ;
    u16* qw  = wqb + 4 * WBSZ;
    u16* kw  = qw + QSZ;
    u16* vw  = qw + 2 * QSZ;
    u8*  mpk = (u8*)(qw + 3 * QSZ);
    u16* cx  = xqb;                 // alias: X-bf16 region is dead by then

    hipLaunchKernelGGL(cvt7m, dim3(2048), dim3(256), 0, stream,
                       Q, K, V, Wq, Wk, Wv, Wo, mask,
                       xqb, xkb, xvb, wqb, wkb, wvb, wob, mpk);
    hipLaunchKernelGGL(qkv_gemm, dim3(NROW / 128, D_ / 128, 3), dim3(256), 0, stream,
                       xqb, xkb, xvb, wqb, wkb, wvb, qw, kw, vw);
    hipLaunchKernelGGL(attn_mfma6, dim3(S_ / 128, H_, B_), dim3(512), 0, stream,
                       qw, kw, vw, mpk, cx);
    hipLaunchKernelGGL(out_gemm, dim3(NROW / 128, D_ / 128), dim3(256), 0, stream,
                       cx, wob, out);
}

// Round 4
// 264.115 us; speedup vs baseline: 1.1134x; 1.1134x over previous
//
#include <hip/hip_runtime.h>

typedef unsigned short u16;
typedef unsigned char  u8;
typedef unsigned long long u64;
typedef __attribute__((ext_vector_type(8))) short bf16x8;   // 8 bf16 in 4 VGPRs
typedef __attribute__((ext_vector_type(4))) float f32x4;

constexpr int B_  = 2;
constexpr int S_  = 2048;
constexpr int D_  = 1024;
constexpr int H_  = 16;
constexpr int DK_ = 64;
constexpr int NROW = B_ * S_;                           // 4096
constexpr size_t QSZ  = (size_t)B_ * H_ * S_ * DK_;     // 4194304 elems per buffer
constexpr size_t XBSZ = (size_t)NROW * D_;              // 4194304 (one X matrix)
constexpr size_t WBSZ = (size_t)D_ * D_;                // 1048576 (one W matrix)
constexpr size_t MSZ  = (size_t)B_ * S_ * S_;           // 8388608 mask elems
constexpr size_t MPKB = MSZ / 8;                        // 1 MiB packed mask bytes

__device__ __forceinline__ u16 f2bf(float f) {
    union { float f; unsigned u; } c; c.f = f;
    unsigned r = c.u + 0x7fffu + ((c.u >> 16) & 1u);    // RNE
    return (u16)(r >> 16);
}
__device__ __forceinline__ unsigned pack2(float a, float b) {
    return (unsigned)f2bf(a) | ((unsigned)f2bf(b) << 16);
}
// HW packed f32->bf16 RNE: dst.lo = bf16(a), dst.hi = bf16(b). Bit-identical
// to f2bf for finite values (exp() outputs are finite positive).
__device__ __forceinline__ unsigned cvt_pk_bf16(float a, float b) {
    unsigned r;
    asm("v_cvt_pk_bf16_f32 %0, %1, %2" : "=v"(r) : "v"(a), "v"(b));
    return r;
}

// async global->LDS, 16B per lane; lds ptr must be wave-uniform base
__device__ __forceinline__ void gl_lds16(const u16* g, u16* l) {
    __builtin_amdgcn_global_load_lds(
        (const __attribute__((address_space(1))) void*)g,
        (__attribute__((address_space(3))) void*)l, 16, 0, 0);
}

// ---------------------------------------------------------------------------
// cvt7m — UNCHANGED from R11. fp32 -> bf16 RNE of X/W + mask bit-pack.
// ---------------------------------------------------------------------------
__global__ __launch_bounds__(256)
void cvt7m(const float* __restrict__ s0, const float* __restrict__ s1,
           const float* __restrict__ s2, const float* __restrict__ s3,
           const float* __restrict__ s4, const float* __restrict__ s5,
           const float* __restrict__ s6, const int* __restrict__ mk,
           u16* __restrict__ d0, u16* __restrict__ d1, u16* __restrict__ d2,
           u16* __restrict__ d3, u16* __restrict__ d4, u16* __restrict__ d5,
           u16* __restrict__ d6, u8* __restrict__ mp)
{
    constexpr size_t XT = 3 * XBSZ;                            // 12582912
    constexpr int NCF = (int)((3 * XBSZ + 4 * WBSZ) / 2048);   // 8192
    constexpr int NCM = (int)(MSZ / 2048);                     // 4096

    for (int c = blockIdx.x; c < NCF + NCM; c += gridDim.x) {
        if (c < NCF) {
            const size_t base = (size_t)c * 2048;
            const float* s; u16* d; size_t off;
            if (base < XT) {
                const int a = (int)(base >> 22);
                off = base & (XBSZ - 1);
                s = (a == 0) ? s0 : (a == 1) ? s1 : s2;
                d = (a == 0) ? d0 : (a == 1) ? d1 : d2;
            } else {
                const size_t r = base - XT;
                const int a = (int)(r >> 20);
                off = r & (WBSZ - 1);
                s = (a == 0) ? s3 : (a == 1) ? s4 : (a == 2) ? s5 : s6;
                d = (a == 0) ? d3 : (a == 1) ? d4 : (a == 2) ? d5 : d6;
            }
            const size_t e = off + (size_t)threadIdx.x * 8;
            const float4 x0 = *(const float4*)(s + e);
            const float4 x1 = *(const float4*)(s + e + 4);
            uint4 p;
            p.x = pack2(x0.x, x0.y); p.y = pack2(x0.z, x0.w);
            p.z = pack2(x1.x, x1.y); p.w = pack2(x1.z, x1.w);
            *(uint4*)(d + e) = p;
        } else {
            const size_t e = (size_t)(c - NCF) * 2048 + (size_t)threadIdx.x * 8;
            const int4 x0 = *(const int4*)(mk + e);
            const int4 x1 = *(const int4*)(mk + e + 4);
            unsigned bv = (unsigned)(x0.x != 0)        | ((unsigned)(x0.y != 0) << 1)
                        | ((unsigned)(x0.z != 0) << 2) | ((unsigned)(x0.w != 0) << 3)
                        | ((unsigned)(x1.x != 0) << 4) | ((unsigned)(x1.y != 0) << 5)
                        | ((unsigned)(x1.z != 0) << 6) | ((unsigned)(x1.w != 0) << 7);
            mp[e >> 3] = (u8)bv;
        }
    }
}

// ---------------------------------------------------------------------------
// qkv_gemm — UNCHANGED from R10.
// ---------------------------------------------------------------------------
__global__ __launch_bounds__(256, 3)
void qkv_gemm(const u16* __restrict__ Xq, const u16* __restrict__ Xk,
              const u16* __restrict__ Xv,
              const u16* __restrict__ Wq, const u16* __restrict__ Wk,
              const u16* __restrict__ Wv,
              u16* __restrict__ Yq, u16* __restrict__ Yk, u16* __restrict__ Yv)
{
    __shared__ u16 As[128 * 32];
    __shared__ u16 Bs[128 * 32];

    const int z = blockIdx.z;
    const u16* X = (z == 0) ? Xq : (z == 1) ? Xk : Xv;
    const u16* W = (z == 0) ? Wq : (z == 1) ? Wk : Wv;
    u16*       Y = (z == 0) ? Yq : (z == 1) ? Yk : Yv;
    const float osc = (z == 0) ? 0.125f : 1.0f;

    const int tid  = threadIdx.x;
    const int lane = tid & 63;
    const int w    = tid >> 6;
    const int quad = lane >> 4;
    const int lq   = lane & 15;
    const int wm   = (w & 1) << 6;
    const int wn   = (w >> 1) << 6;

    const int m0 = blockIdx.x << 7;
    const int n0 = blockIdx.y << 7;

    const int srow = tid >> 2;
    const int scol = (tid & 3) << 3;
    const u16* ga0 = X + (size_t)(m0 + srow) * D_ + scol;
    const u16* ga1 = ga0 + (size_t)64 * D_;
    const u16* gb0 = W + (size_t)(n0 + srow) * D_ + scol;
    const u16* gb1 = gb0 + (size_t)64 * D_;

    u16* la0 = As + (size_t)w * 512;
    u16* la1 = As + 2048 + (size_t)w * 512;
    u16* lb0 = Bs + (size_t)w * 512;
    u16* lb1 = Bs + 2048 + (size_t)w * 512;

    f32x4 acc[4][4];
#pragma unroll
    for (int i = 0; i < 4; ++i)
#pragma unroll
        for (int j = 0; j < 4; ++j) acc[i][j] = (f32x4){0.f, 0.f, 0.f, 0.f};

    for (int kt = 0; kt < D_; kt += 32) {
        __syncthreads();
        gl_lds16(ga0 + kt, la0);
        gl_lds16(ga1 + kt, la1);
        gl_lds16(gb0 + kt, lb0);
        gl_lds16(gb1 + kt, lb1);
        __syncthreads();

        bf16x8 af[4], bf[4];
#pragma unroll
        for (int t = 0; t < 4; ++t) {
            af[t] = *(const bf16x8*)&As[(size_t)(wm + (t << 4) + lq) * 32 + (quad << 3)];
            bf[t] = *(const bf16x8*)&Bs[(size_t)(wn + (t << 4) + lq) * 32 + (quad << 3)];
        }
#pragma unroll
        for (int i = 0; i < 4; ++i)
#pragma unroll
            for (int j = 0; j < 4; ++j)
                acc[i][j] = __builtin_amdgcn_mfma_f32_16x16x32_bf16(
                    af[i], bf[j], acc[i][j], 0, 0, 0);
    }

#pragma unroll
    for (int i = 0; i < 4; ++i)
#pragma unroll
        for (int j = 0; j < 4; ++j)
#pragma unroll
            for (int r = 0; r < 4; ++r) {
                const int grow = m0 + wm + (i << 4) + (quad << 2) + r;
                const int of   = n0 + wn + (j << 4) + lq;
                const int b = grow >> 11, s = grow & (S_ - 1);
                const int h = of >> 6,    dk = of & 63;
                Y[(((size_t)(b * H_ + h)) * S_ + s) * DK_ + dk] =
                    f2bf(acc[i][j][r] * osc);
            }
}

// ---------------------------------------------------------------------------
// out_gemm — UNCHANGED from R10.
// ---------------------------------------------------------------------------
__global__ __launch_bounds__(256, 3)
void out_gemm(const u16* __restrict__ X, const u16* __restrict__ W,
              float* __restrict__ Y)
{
    __shared__ u16 As[128 * 32];
    __shared__ u16 Bs[128 * 32];

    const int tid  = threadIdx.x;
    const int lane = tid & 63;
    const int w    = tid >> 6;
    const int quad = lane >> 4;
    const int lq   = lane & 15;
    const int wm   = (w & 1) << 6;
    const int wn   = (w >> 1) << 6;

    const int m0 = blockIdx.x << 7;
    const int n0 = blockIdx.y << 7;

    const int srow = tid >> 2;
    const int scol = (tid & 3) << 3;
    const u16* ga0 = X + (size_t)(m0 + srow) * D_ + scol;
    const u16* ga1 = ga0 + (size_t)64 * D_;
    const u16* gb0 = W + (size_t)(n0 + srow) * D_ + scol;
    const u16* gb1 = gb0 + (size_t)64 * D_;

    u16* la0 = As + (size_t)w * 512;
    u16* la1 = As + 2048 + (size_t)w * 512;
    u16* lb0 = Bs + (size_t)w * 512;
    u16* lb1 = Bs + 2048 + (size_t)w * 512;

    f32x4 acc[4][4];
#pragma unroll
    for (int i = 0; i < 4; ++i)
#pragma unroll
        for (int j = 0; j < 4; ++j) acc[i][j] = (f32x4){0.f, 0.f, 0.f, 0.f};

    for (int kt = 0; kt < D_; kt += 32) {
        __syncthreads();
        gl_lds16(ga0 + kt, la0);
        gl_lds16(ga1 + kt, la1);
        gl_lds16(gb0 + kt, lb0);
        gl_lds16(gb1 + kt, lb1);
        __syncthreads();

        bf16x8 af[4], bf[4];
#pragma unroll
        for (int t = 0; t < 4; ++t) {
            af[t] = *(const bf16x8*)&As[(size_t)(wm + (t << 4) + lq) * 32 + (quad << 3)];
            bf[t] = *(const bf16x8*)&Bs[(size_t)(wn + (t << 4) + lq) * 32 + (quad << 3)];
        }
#pragma unroll
        for (int i = 0; i < 4; ++i)
#pragma unroll
            for (int j = 0; j < 4; ++j)
                acc[i][j] = __builtin_amdgcn_mfma_f32_16x16x32_bf16(
                    af[i], bf[j], acc[i][j], 0, 0, 0);
    }

#pragma unroll
    for (int i = 0; i < 4; ++i)
#pragma unroll
        for (int j = 0; j < 4; ++j)
#pragma unroll
            for (int r = 0; r < 4; ++r) {
                const int grow = m0 + wm + (i << 4) + (quad << 2) + r;
                const int gcol = n0 + wn + (j << 4) + lq;
                Y[(size_t)grow * D_ + gcol] = acc[i][j][r];
            }
}

// ---------------------------------------------------------------------------
// attn_mfma7 (R13): QBLK=64 to lift the grid occupancy cap. 1024 blocks =
// 4 blocks/CU (was 512 = 2/CU), 256 thr / 4 waves, each wave owns 16 q-rows.
// Inner chunk math byte-identical to R11 (masks, exp, cvt_pk, MFMA order per
// q-row) -> bit-identical output. Q frags direct from global (L3-resident;
// frees Qs LDS). ~95 VGPR live fits the 128-cap of (256,4): no spill (R12's
// failure was scratch at the 512-thread 128-cap). Bijective XCD swizzle keeps
// each XCD on 4 (b,h) pairs -> K/V L2-resident.
// ---------------------------------------------------------------------------
constexpr int AP = 72;

__global__ __launch_bounds__(256, 4)
void attn_mfma7(const u16* __restrict__ qb, const u16* __restrict__ kb,
                const u16* __restrict__ vb, const u8* __restrict__ mpk,
                u16* __restrict__ ctx)
{
    __shared__ __align__(16) u16 Ks[64][AP];
    __shared__ __align__(16) u16 Vt[64][AP];     // [d][pi(key)]
    __shared__ __align__(16) u16 Ps[64][AP];     // [q][pi(key)]

    const int tid  = threadIdx.x;
    const int lane = tid & 63;
    const int w    = tid >> 6;             // 0..3
    const int quad = lane >> 4;
    const int lq   = lane & 15;
    const int w16  = w << 4;               // wave's 16-row base

    // bijective XCD swizzle: hw block bid lands on XCD (bid&7); give each XCD
    // a contiguous run of logical tiles so same-(b,h) blocks share an L2.
    const int bid = blockIdx.x + (int)(gridDim.x * (blockIdx.y + gridDim.y * blockIdx.z));
    const int nwg = (int)(gridDim.x * gridDim.y * gridDim.z);      // 1024
    const int swz = (bid & 7) * (nwg >> 3) + (bid >> 3);
    const int qt = swz & 31;               // q-tile (32 per head)
    const int h  = (swz >> 5) & 15;
    const int b  = swz >> 9;

    const int q0 = qt << 6;

    const u16* qbh = qb + (((size_t)b * H_ + h) * S_ + q0) * DK_;
    const u16* kbh = kb + ((size_t)b * H_ + h) * S_ * DK_;
    const u16* vbh = vb + ((size_t)b * H_ + h) * S_ * DK_;

    // Q fragments straight from global (one-time, L3-resident)
    bf16x8 aQ0, aQ1;
    {
        const size_t qr = (size_t)(w16 + lq) * DK_;
        aQ0 = *(const bf16x8*)&qbh[qr + (quad << 3)];
        aQ1 = *(const bf16x8*)&qbh[qr + 32 + (quad << 3)];
    }

    f32x4 O[4];
    float lsum[4];
#pragma unroll
    for (int t = 0; t < 4; ++t) O[t] = (f32x4){0.f, 0.f, 0.f, 0.f};
#pragma unroll
    for (int r = 0; r < 4; ++r) lsum[r] = 0.f;

    // staging maps (256 threads stage K[64][64] and V[64][64])
    const int ksr = tid >> 2, ksc = (tid & 3) << 4;
    const int vkey = lane, vsc = w << 4;
    const int vpc  = ((vkey & 15) << 2) | (vkey >> 4);   // pi(key)

    uint4 kr0, kr1; ushort4 vr[4];
    {
        kr0 = *(const uint4*)&kbh[(size_t)ksr * DK_ + ksc];
        kr1 = *(const uint4*)&kbh[(size_t)ksr * DK_ + ksc + 8];
#pragma unroll
        for (int u = 0; u < 4; ++u)
            vr[u] = *(const ushort4*)&vbh[(size_t)vkey * DK_ + vsc + (u << 2)];
    }

    const int qrow0 = q0 + w16 + (quad << 2);
    const u8* mrow = mpk + (size_t)b * S_ * (S_ / 8) + (size_t)qrow0 * (S_ / 8);

    for (int k0 = 0; k0 < S_; k0 += 64) {
        // packed mask: one u64 (64 key-bits) per q-row handled by this thread
        u64 mw[4];
#pragma unroll
        for (int r = 0; r < 4; ++r)
            mw[r] = *(const u64*)&mrow[(size_t)r * (S_ / 8) + (k0 >> 3)];

        __syncthreads();
        {   // staged regs -> LDS
            *(uint4*)&Ks[ksr][ksc]     = kr0;
            *(uint4*)&Ks[ksr][ksc + 8] = kr1;
            const u16 vv[16] = {
                vr[0].x, vr[0].y, vr[0].z, vr[0].w,
                vr[1].x, vr[1].y, vr[1].z, vr[1].w,
                vr[2].x, vr[2].y, vr[2].z, vr[2].w,
                vr[3].x, vr[3].y, vr[3].z, vr[3].w };
#pragma unroll
            for (int i = 0; i < 16; ++i)
                Vt[vsc + i][vpc] = vv[i];
        }
        __syncthreads();

        if (k0 + 64 < S_) {   // prefetch next chunk
            const size_t kb0 = (size_t)(k0 + 64 + ksr) * DK_ + ksc;
            kr0 = *(const uint4*)&kbh[kb0];
            kr1 = *(const uint4*)&kbh[kb0 + 8];
            const size_t vb0 = (size_t)(k0 + 64 + vkey) * DK_ + vsc;
#pragma unroll
            for (int u = 0; u < 4; ++u)
                vr[u] = *(const ushort4*)&vbh[vb0 + (u << 2)];
        }

        // ---- S = Q K^T ----
        f32x4 st[4];
#pragma unroll
        for (int t = 0; t < 4; ++t) {
            const bf16x8 b0 = *(const bf16x8*)&Ks[(t << 4) + lq][quad << 3];
            const bf16x8 b1 = *(const bf16x8*)&Ks[(t << 4) + lq][32 + (quad << 3)];
            f32x4 c = {0.f, 0.f, 0.f, 0.f};
            c = __builtin_amdgcn_mfma_f32_16x16x32_bf16(aQ0, b0, c, 0, 0, 0);
            c = __builtin_amdgcn_mfma_f32_16x16x32_bf16(aQ1, b1, c, 0, 0, 0);
            st[t] = c;
        }

        // ---- exp (fixed base; scale pre-folded), l partials, P pack ----
#pragma unroll
        for (int r = 0; r < 4; ++r) {
            const unsigned lo = (unsigned)mw[r];
            const unsigned hi = (unsigned)(mw[r] >> 32);
            float p0 = __expf(st[0][r]);
            float p1 = __expf(st[1][r]);
            float p2 = __expf(st[2][r]);
            float p3 = __expf(st[3][r]);
            p0 = ((lo >> lq) & 1u) ? p0 : 1.0f;          // key = k0 + 0*16 + lq
            p1 = ((lo >> (lq + 16)) & 1u) ? p1 : 1.0f;   // key = k0 + 1*16 + lq
            p2 = ((hi >> lq) & 1u) ? p2 : 1.0f;          // key = k0 + 2*16 + lq
            p3 = ((hi >> (lq + 16)) & 1u) ? p3 : 1.0f;   // key = k0 + 3*16 + lq
            lsum[r] += (p0 + p1) + (p2 + p3);
            uint2 pw;
            pw.x = cvt_pk_bf16(p0, p1);
            pw.y = cvt_pk_bf16(p2, p3);
            *(uint2*)&Ps[w16 + (quad << 2) + r][lq << 2] = pw;
        }

        // ---- O += P V (wave-local Ps rows: DS in-order, no barrier) ----
        bf16x8 aP0, aP1;
        aP0 = *(const bf16x8*)&Ps[w16 + lq][quad << 3];
        aP1 = *(const bf16x8*)&Ps[w16 + lq][32 + (quad << 3)];
#pragma unroll
        for (int t = 0; t < 4; ++t) {
            const bf16x8 b0 = *(const bf16x8*)&Vt[(t << 4) + lq][quad << 3];
            const bf16x8 b1 = *(const bf16x8*)&Vt[(t << 4) + lq][32 + (quad << 3)];
            O[t] = __builtin_amdgcn_mfma_f32_16x16x32_bf16(aP0, b0, O[t], 0, 0, 0);
            O[t] = __builtin_amdgcn_mfma_f32_16x16x32_bf16(aP1, b1, O[t], 0, 0, 0);
        }
    }

    // deferred l reduction (16 lanes of the quad)
#pragma unroll
    for (int r = 0; r < 4; ++r) {
#pragma unroll
        for (int off = 1; off < 16; off <<= 1)
            lsum[r] += __shfl_xor(lsum[r], off);
        lsum[r] = 1.0f / lsum[r];
    }

    // epilogue: bf16 ctx [b, s, h*64 + d]
#pragma unroll
    for (int t = 0; t < 4; ++t)
#pragma unroll
        for (int r = 0; r < 4; ++r) {
            const int row = qrow0 + r;
            ctx[((size_t)b * S_ + row) * D_ + (h << 6) + (t << 4) + lq] =
                f2bf(O[t][r] * lsum[r]);
        }
}

// ---------------------------------------------------------------------------
// Workspace layout (u16 units), ~61 MB total (unchanged from R11):
//   [0)              xqb,xkb,xvb : 3*XBSZ  (bf16 X; dead after qkv_gemm)
//   [3*XBSZ)         wqb..wob    : 4*WBSZ  (bf16 W)
//   [3*XBSZ+4*WBSZ)  qw,kw,vw    : 3*QSZ
//   after that       mpk         : MPKB bytes (bit-packed mask)
//   cx aliases xqb (attn writes it after qkv_gemm's last read of xvb).
// ---------------------------------------------------------------------------
extern "C" void kernel_launch(void* const* d_in, const int* in_sizes, int n_in,
                              void* d_out, int out_size, void* d_ws, size_t ws_size,
                              hipStream_t stream)
{
    const float* Q    = (const float*)d_in[0];
    const float* K    = (const float*)d_in[1];
    const float* V    = (const float*)d_in[2];
    const int*   mask = (const int*)d_in[3];
    const float* Wq   = (const float*)d_in[4];
    const float* Wk   = (const float*)d_in[5];
    const float* Wv   = (const float*)d_in[6];
    const float* Wo   = (const float*)d_in[7];
    float* out = (float*)d_out;

    u16* xqb = (u16*)d_ws;
    u16* xkb = xqb + XBSZ;
    u16* xvb = xqb + 2 * XBSZ;
    u16* wqb = xqb + 3 * XBSZ;
    u16* wkb = wqb + WBSZ;
    u16* wvb = wqb + 2 * WBSZ;
    u16* wob = wqb + 3 * WBSZ;
    u16* qw  = wqb + 4 * WBSZ;
    u16* kw  = qw + QSZ;
    u16* vw  = qw + 2 * QSZ;
    u8*  mpk = (u8*)(qw + 3 * QSZ);
    u16* cx  = xqb;                 // alias: X-bf16 region is dead by then

    hipLaunchKernelGGL(cvt7m, dim3(2048), dim3(256), 0, stream,
                       Q, K, V, Wq, Wk, Wv, Wo, mask,
                       xqb, xkb, xvb, wqb, wkb, wvb, wob, mpk);
    hipLaunchKernelGGL(qkv_gemm, dim3(NROW / 128, D_ / 128, 3), dim3(256), 0, stream,
                       xqb, xkb, xvb, wqb, wkb, wvb, qw, kw, vw);
    hipLaunchKernelGGL(attn_mfma7, dim3(S_ / 64, H_, B_), dim3(256), 0, stream,
                       qw, kw, vw, mpk, cx);
    hipLaunchKernelGGL(out_gemm, dim3(NROW / 128, D_ / 128), dim3(256), 0, stream,
                       cx, wob, out);
}

// Round 5
// 251.984 us; speedup vs baseline: 1.1670x; 1.0481x over previous
//
#include <hip/hip_runtime.h>

typedef unsigned short u16;
typedef unsigned char  u8;
typedef unsigned long long u64;
typedef __attribute__((ext_vector_type(8))) short bf16x8;   // 8 bf16 in 4 VGPRs
typedef __attribute__((ext_vector_type(4))) float f32x4;

constexpr int B_  = 2;
constexpr int S_  = 2048;
constexpr int D_  = 1024;
constexpr int H_  = 16;
constexpr int DK_ = 64;
constexpr int NROW = B_ * S_;                           // 4096
constexpr size_t QSZ  = (size_t)B_ * H_ * S_ * DK_;     // 4194304 elems per buffer
constexpr size_t XBSZ = (size_t)NROW * D_;              // 4194304 (one X matrix)
constexpr size_t WBSZ = (size_t)D_ * D_;                // 1048576 (one W matrix)
constexpr size_t MSZ  = (size_t)B_ * S_ * S_;           // 8388608 mask elems
constexpr size_t MPKB = MSZ / 8;                        // 1 MiB packed mask bytes

__device__ __forceinline__ u16 f2bf(float f) {
    union { float f; unsigned u; } c; c.f = f;
    unsigned r = c.u + 0x7fffu + ((c.u >> 16) & 1u);    // RNE
    return (u16)(r >> 16);
}
__device__ __forceinline__ unsigned pack2(float a, float b) {
    return (unsigned)f2bf(a) | ((unsigned)f2bf(b) << 16);
}
// HW packed f32->bf16 RNE: bit-identical to f2bf for finite values.
__device__ __forceinline__ unsigned cvt_pk_bf16(float a, float b) {
    unsigned r;
    asm("v_cvt_pk_bf16_f32 %0, %1, %2" : "=v"(r) : "v"(a), "v"(b));
    return r;
}

// async global->LDS, 16B per lane; lds ptr must be wave-uniform base
__device__ __forceinline__ void gl_lds16(const u16* g, u16* l) {
    __builtin_amdgcn_global_load_lds(
        (const __attribute__((address_space(1))) void*)g,
        (__attribute__((address_space(3))) void*)l, 16, 0, 0);
}

// ---------------------------------------------------------------------------
// cvt7m — UNCHANGED from R11. fp32 -> bf16 RNE of X/W + mask bit-pack.
// ---------------------------------------------------------------------------
__global__ __launch_bounds__(256)
void cvt7m(const float* __restrict__ s0, const float* __restrict__ s1,
           const float* __restrict__ s2, const float* __restrict__ s3,
           const float* __restrict__ s4, const float* __restrict__ s5,
           const float* __restrict__ s6, const int* __restrict__ mk,
           u16* __restrict__ d0, u16* __restrict__ d1, u16* __restrict__ d2,
           u16* __restrict__ d3, u16* __restrict__ d4, u16* __restrict__ d5,
           u16* __restrict__ d6, u8* __restrict__ mp)
{
    constexpr size_t XT = 3 * XBSZ;                            // 12582912
    constexpr int NCF = (int)((3 * XBSZ + 4 * WBSZ) / 2048);   // 8192
    constexpr int NCM = (int)(MSZ / 2048);                     // 4096

    for (int c = blockIdx.x; c < NCF + NCM; c += gridDim.x) {
        if (c < NCF) {
            const size_t base = (size_t)c * 2048;
            const float* s; u16* d; size_t off;
            if (base < XT) {
                const int a = (int)(base >> 22);
                off = base & (XBSZ - 1);
                s = (a == 0) ? s0 : (a == 1) ? s1 : s2;
                d = (a == 0) ? d0 : (a == 1) ? d1 : d2;
            } else {
                const size_t r = base - XT;
                const int a = (int)(r >> 20);
                off = r & (WBSZ - 1);
                s = (a == 0) ? s3 : (a == 1) ? s4 : (a == 2) ? s5 : s6;
                d = (a == 0) ? d3 : (a == 1) ? d4 : (a == 2) ? d5 : d6;
            }
            const size_t e = off + (size_t)threadIdx.x * 8;
            const float4 x0 = *(const float4*)(s + e);
            const float4 x1 = *(const float4*)(s + e + 4);
            uint4 p;
            p.x = pack2(x0.x, x0.y); p.y = pack2(x0.z, x0.w);
            p.z = pack2(x1.x, x1.y); p.w = pack2(x1.z, x1.w);
            *(uint4*)(d + e) = p;
        } else {
            const size_t e = (size_t)(c - NCF) * 2048 + (size_t)threadIdx.x * 8;
            const int4 x0 = *(const int4*)(mk + e);
            const int4 x1 = *(const int4*)(mk + e + 4);
            unsigned bv = (unsigned)(x0.x != 0)        | ((unsigned)(x0.y != 0) << 1)
                        | ((unsigned)(x0.z != 0) << 2) | ((unsigned)(x0.w != 0) << 3)
                        | ((unsigned)(x1.x != 0) << 4) | ((unsigned)(x1.y != 0) << 5)
                        | ((unsigned)(x1.z != 0) << 6) | ((unsigned)(x1.w != 0) << 7);
            mp[e >> 3] = (u8)bv;
        }
    }
}

// ---------------------------------------------------------------------------
// qkv_gemm (R14): BK=64 as two stacked [128][32] half-tiles per barrier
// window (keeps the 2-way-free ds_read pattern + linear gl_lds16 dests).
// Barrier pairs 32 -> 16, 32 MFMA per window. K order unchanged -> bit-exact.
// ---------------------------------------------------------------------------
__global__ __launch_bounds__(256, 3)
void qkv_gemm(const u16* __restrict__ Xq, const u16* __restrict__ Xk,
              const u16* __restrict__ Xv,
              const u16* __restrict__ Wq, const u16* __restrict__ Wk,
              const u16* __restrict__ Wv,
              u16* __restrict__ Yq, u16* __restrict__ Yk, u16* __restrict__ Yv)
{
    __shared__ u16 As[2 * 128 * 32];    // [kk][row][col]
    __shared__ u16 Bs[2 * 128 * 32];

    const int z = blockIdx.z;
    const u16* X = (z == 0) ? Xq : (z == 1) ? Xk : Xv;
    const u16* W = (z == 0) ? Wq : (z == 1) ? Wk : Wv;
    u16*       Y = (z == 0) ? Yq : (z == 1) ? Yk : Yv;
    const float osc = (z == 0) ? 0.125f : 1.0f;

    const int tid  = threadIdx.x;
    const int lane = tid & 63;
    const int w    = tid >> 6;
    const int quad = lane >> 4;
    const int lq   = lane & 15;
    const int wm   = (w & 1) << 6;
    const int wn   = (w >> 1) << 6;

    const int m0 = blockIdx.x << 7;
    const int n0 = blockIdx.y << 7;

    const int srow = tid >> 2;
    const int scol = (tid & 3) << 3;
    const u16* ga0 = X + (size_t)(m0 + srow) * D_ + scol;
    const u16* ga1 = ga0 + (size_t)64 * D_;
    const u16* gb0 = W + (size_t)(n0 + srow) * D_ + scol;
    const u16* gb1 = gb0 + (size_t)64 * D_;

    u16* la0 = As + (size_t)w * 512;
    u16* la1 = As + 2048 + (size_t)w * 512;
    u16* lb0 = Bs + (size_t)w * 512;
    u16* lb1 = Bs + 2048 + (size_t)w * 512;

    f32x4 acc[4][4];
#pragma unroll
    for (int i = 0; i < 4; ++i)
#pragma unroll
        for (int j = 0; j < 4; ++j) acc[i][j] = (f32x4){0.f, 0.f, 0.f, 0.f};

    for (int kt = 0; kt < D_; kt += 64) {
        __syncthreads();
        gl_lds16(ga0 + kt, la0);
        gl_lds16(ga1 + kt, la1);
        gl_lds16(gb0 + kt, lb0);
        gl_lds16(gb1 + kt, lb1);
        gl_lds16(ga0 + kt + 32, la0 + 4096);
        gl_lds16(ga1 + kt + 32, la1 + 4096);
        gl_lds16(gb0 + kt + 32, lb0 + 4096);
        gl_lds16(gb1 + kt + 32, lb1 + 4096);
        __syncthreads();

#pragma unroll
        for (int kk = 0; kk < 2; ++kk) {
            bf16x8 af[4], bf[4];
#pragma unroll
            for (int t = 0; t < 4; ++t) {
                af[t] = *(const bf16x8*)&As[(kk << 12) + (size_t)(wm + (t << 4) + lq) * 32 + (quad << 3)];
                bf[t] = *(const bf16x8*)&Bs[(kk << 12) + (size_t)(wn + (t << 4) + lq) * 32 + (quad << 3)];
            }
#pragma unroll
            for (int i = 0; i < 4; ++i)
#pragma unroll
                for (int j = 0; j < 4; ++j)
                    acc[i][j] = __builtin_amdgcn_mfma_f32_16x16x32_bf16(
                        af[i], bf[j], acc[i][j], 0, 0, 0);
        }
    }

#pragma unroll
    for (int i = 0; i < 4; ++i)
#pragma unroll
        for (int j = 0; j < 4; ++j)
#pragma unroll
            for (int r = 0; r < 4; ++r) {
                const int grow = m0 + wm + (i << 4) + (quad << 2) + r;
                const int of   = n0 + wn + (j << 4) + lq;
                const int b = grow >> 11, s = grow & (S_ - 1);
                const int h = of >> 6,    dk = of & 63;
                Y[(((size_t)(b * H_ + h)) * S_ + s) * DK_ + dk] =
                    f2bf(acc[i][j][r] * osc);
            }
}

// ---------------------------------------------------------------------------
// out_gemm (R14): 64x64 tile (grid 1024 = 4 blocks/CU; was 256 = 1/CU!),
// BK=64 stacked half-tiles. B-panels (128 KB) are L2-resident so the extra
// re-reads are cheap. K order unchanged -> bit-exact.
// ---------------------------------------------------------------------------
__global__ __launch_bounds__(256, 4)
void out_gemm(const u16* __restrict__ X, const u16* __restrict__ W,
              float* __restrict__ Y)
{
    __shared__ u16 As[2 * 64 * 32];
    __shared__ u16 Bs[2 * 64 * 32];

    const int tid  = threadIdx.x;
    const int lane = tid & 63;
    const int w    = tid >> 6;
    const int quad = lane >> 4;
    const int lq   = lane & 15;
    const int wm   = (w & 1) << 5;
    const int wn   = (w >> 1) << 5;

    const int m0 = blockIdx.x << 6;
    const int n0 = blockIdx.y << 6;

    const int srow = tid >> 2;          // 0..63
    const int scol = (tid & 3) << 3;
    const u16* ga0 = X + (size_t)(m0 + srow) * D_ + scol;
    const u16* gb0 = W + (size_t)(n0 + srow) * D_ + scol;

    u16* la0 = As + (size_t)w * 512;
    u16* lb0 = Bs + (size_t)w * 512;

    f32x4 acc[2][2];
#pragma unroll
    for (int i = 0; i < 2; ++i)
#pragma unroll
        for (int j = 0; j < 2; ++j) acc[i][j] = (f32x4){0.f, 0.f, 0.f, 0.f};

    for (int kt = 0; kt < D_; kt += 64) {
        __syncthreads();
        gl_lds16(ga0 + kt, la0);
        gl_lds16(gb0 + kt, lb0);
        gl_lds16(ga0 + kt + 32, la0 + 2048);
        gl_lds16(gb0 + kt + 32, lb0 + 2048);
        __syncthreads();

#pragma unroll
        for (int kk = 0; kk < 2; ++kk) {
            bf16x8 af[2], bf[2];
#pragma unroll
            for (int t = 0; t < 2; ++t) {
                af[t] = *(const bf16x8*)&As[(kk << 11) + (size_t)(wm + (t << 4) + lq) * 32 + (quad << 3)];
                bf[t] = *(const bf16x8*)&Bs[(kk << 11) + (size_t)(wn + (t << 4) + lq) * 32 + (quad << 3)];
            }
#pragma unroll
            for (int i = 0; i < 2; ++i)
#pragma unroll
                for (int j = 0; j < 2; ++j)
                    acc[i][j] = __builtin_amdgcn_mfma_f32_16x16x32_bf16(
                        af[i], bf[j], acc[i][j], 0, 0, 0);
        }
    }

#pragma unroll
    for (int i = 0; i < 2; ++i)
#pragma unroll
        for (int j = 0; j < 2; ++j)
#pragma unroll
            for (int r = 0; r < 4; ++r) {
                const int grow = m0 + wm + (i << 4) + (quad << 2) + r;
                const int gcol = n0 + wn + (j << 4) + lq;
                Y[(size_t)grow * D_ + gcol] = acc[i][j][r];
            }
}

// ---------------------------------------------------------------------------
// attn_mfma8 (R14): exact R11 structure (QBLK=128, 4 waves, best measured
// 73.7 us) + two additions:
//  (a) bijective XCD swizzle (R13 evidence: FETCH 70 -> 14 MB) so each XCD's
//      64 co-resident blocks cover 4 (b,h) pairs -> K/V L2-resident.
//  (b) conflict-free Vt staging: thread owns key-pair (k,k+16) (adjacent
//      pi columns), writes 8 ushort2 -> bank (d*36+2c+s)%32 is a permutation
//      per half-wave. Same Vt[d][pi(k)] contents -> bit-identical.
// ---------------------------------------------------------------------------
constexpr int AP = 72;

__global__ __launch_bounds__(256, 2)
void attn_mfma8(const u16* __restrict__ qb, const u16* __restrict__ kb,
                const u16* __restrict__ vb, const u8* __restrict__ mpk,
                u16* __restrict__ ctx)
{
    __shared__ u16 Qs[128][AP];
    __shared__ u16 Ks[64][AP];
    __shared__ u16 Vt[64][AP];     // [d][pi(key)]
    __shared__ u16 Ps[128][AP];    // [q][pi(key)]

    const int tid  = threadIdx.x;
    const int lane = tid & 63;
    const int w    = tid >> 6;
    const int quad = lane >> 4;
    const int lq   = lane & 15;
    const int w32  = w << 5;

    // bijective XCD swizzle: XCD (bid&7) gets a contiguous run of 64 logical
    // tiles = 4 (b,h) pairs -> K/V (2 MB) resident in that XCD's L2.
    const int bid = (int)(blockIdx.x + gridDim.x * (blockIdx.y + gridDim.y * blockIdx.z));
    const int swz = (bid & 7) * 64 + (bid >> 3);        // nwg = 512
    const int q0 = (swz & 15) << 7;
    const int h  = (swz >> 4) & 15;
    const int b  = swz >> 8;

    const u16* qbh = qb + (((size_t)b * H_ + h) * S_ + q0) * DK_;
    const u16* kbh = kb + ((size_t)b * H_ + h) * S_ * DK_;
    const u16* vbh = vb + ((size_t)b * H_ + h) * S_ * DK_;

    {   // stage Q tile [128][64]
        const int r = tid >> 1, c = (tid & 1) << 5;
#pragma unroll
        for (int u = 0; u < 4; ++u)
            *(uint4*)&Qs[r][c + (u << 3)] =
                *(const uint4*)&qbh[(size_t)r * DK_ + c + (u << 3)];
    }
    __syncthreads();
    bf16x8 aQ[2][2];
#pragma unroll
    for (int i = 0; i < 2; ++i) {
        aQ[i][0] = *(const bf16x8*)&Qs[w32 + (i << 4) + lq][quad << 3];
        aQ[i][1] = *(const bf16x8*)&Qs[w32 + (i << 4) + lq][32 + (quad << 3)];
    }

    f32x4 O[2][4];
    float lsum[2][4];
#pragma unroll
    for (int i = 0; i < 2; ++i)
#pragma unroll
        for (int t = 0; t < 4; ++t) O[i][t] = (f32x4){0.f, 0.f, 0.f, 0.f};
#pragma unroll
    for (int i = 0; i < 2; ++i)
#pragma unroll
        for (int r = 0; r < 4; ++r) lsum[i][r] = 0.f;

    // K staging map (unchanged)
    const int ksr = tid >> 2, ksc = (tid & 3) << 4;
    // V staging map (new): thread -> key-pair (vk0, vk0+16), 8 d's
    const int vc  = tid & 15;            // c
    const int vs  = (tid >> 4) & 1;      // s
    const int vk0 = vc + (vs << 5);      // keys vk0 and vk0+16
    const int vdg = tid >> 5;            // d-group (8 d's)
    const int vcol = (vc << 2) + (vs << 1);  // pi(vk0); pi(vk0+16) = vcol+1

    uint4 kr0, kr1, vr0, vr1;
    {
        kr0 = *(const uint4*)&kbh[(size_t)ksr * DK_ + ksc];
        kr1 = *(const uint4*)&kbh[(size_t)ksr * DK_ + ksc + 8];
        vr0 = *(const uint4*)&vbh[(size_t)vk0 * DK_ + (vdg << 3)];
        vr1 = *(const uint4*)&vbh[(size_t)(vk0 + 16) * DK_ + (vdg << 3)];
    }

    const int qrow0 = q0 + w32 + (quad << 2);
    const u8* mrow = mpk + (size_t)b * S_ * (S_ / 8) + (size_t)qrow0 * (S_ / 8);

    for (int k0 = 0; k0 < S_; k0 += 64) {
        u64 mw[2][4];
#pragma unroll
        for (int i = 0; i < 2; ++i)
#pragma unroll
            for (int r = 0; r < 4; ++r)
                mw[i][r] = *(const u64*)&mrow[(size_t)((i << 4) + r) * (S_ / 8) + (k0 >> 3)];

        __syncthreads();
        {   // staged regs -> LDS
            *(uint4*)&Ks[ksr][ksc]     = kr0;
            *(uint4*)&Ks[ksr][ksc + 8] = kr1;
            const u16* a0 = (const u16*)&vr0;
            const u16* a1 = (const u16*)&vr1;
#pragma unroll
            for (int i = 0; i < 8; ++i)
                *(ushort2*)&Vt[(vdg << 3) + i][vcol] = (ushort2){a0[i], a1[i]};
        }
        __syncthreads();

        if (k0 + 64 < S_) {   // prefetch next chunk
            const size_t kb0 = (size_t)(k0 + 64 + ksr) * DK_ + ksc;
            kr0 = *(const uint4*)&kbh[kb0];
            kr1 = *(const uint4*)&kbh[kb0 + 8];
            const size_t vb0 = (size_t)(k0 + 64 + vk0) * DK_ + (vdg << 3);
            vr0 = *(const uint4*)&vbh[vb0];
            vr1 = *(const uint4*)&vbh[vb0 + (size_t)16 * DK_];
        }

        // ---- S = Q K^T : K frags shared across both row-groups ----
        f32x4 st[2][4];
#pragma unroll
        for (int t = 0; t < 4; ++t) {
            const bf16x8 b0 = *(const bf16x8*)&Ks[(t << 4) + lq][quad << 3];
            const bf16x8 b1 = *(const bf16x8*)&Ks[(t << 4) + lq][32 + (quad << 3)];
#pragma unroll
            for (int i = 0; i < 2; ++i) {
                f32x4 c = {0.f, 0.f, 0.f, 0.f};
                c = __builtin_amdgcn_mfma_f32_16x16x32_bf16(aQ[i][0], b0, c, 0, 0, 0);
                c = __builtin_amdgcn_mfma_f32_16x16x32_bf16(aQ[i][1], b1, c, 0, 0, 0);
                st[i][t] = c;
            }
        }

        // ---- exp (fixed base), masked selects, l partials, P pack ----
#pragma unroll
        for (int i = 0; i < 2; ++i)
#pragma unroll
            for (int r = 0; r < 4; ++r) {
                const unsigned lo = (unsigned)mw[i][r];
                const unsigned hi = (unsigned)(mw[i][r] >> 32);
                float p0 = __expf(st[i][0][r]);
                float p1 = __expf(st[i][1][r]);
                float p2 = __expf(st[i][2][r]);
                float p3 = __expf(st[i][3][r]);
                p0 = ((lo >> lq) & 1u) ? p0 : 1.0f;
                p1 = ((lo >> (lq + 16)) & 1u) ? p1 : 1.0f;
                p2 = ((hi >> lq) & 1u) ? p2 : 1.0f;
                p3 = ((hi >> (lq + 16)) & 1u) ? p3 : 1.0f;
                lsum[i][r] += (p0 + p1) + (p2 + p3);
                uint2 pw;
                pw.x = cvt_pk_bf16(p0, p1);
                pw.y = cvt_pk_bf16(p2, p3);
                *(uint2*)&Ps[w32 + (i << 4) + (quad << 2) + r][lq << 2] = pw;
            }

        // ---- O += P V (wave-local Ps rows: DS in-order, no barrier) ----
        bf16x8 aP[2][2];
#pragma unroll
        for (int i = 0; i < 2; ++i) {
            aP[i][0] = *(const bf16x8*)&Ps[w32 + (i << 4) + lq][quad << 3];
            aP[i][1] = *(const bf16x8*)&Ps[w32 + (i << 4) + lq][32 + (quad << 3)];
        }
#pragma unroll
        for (int t = 0; t < 4; ++t) {
            const bf16x8 b0 = *(const bf16x8*)&Vt[(t << 4) + lq][quad << 3];
            const bf16x8 b1 = *(const bf16x8*)&Vt[(t << 4) + lq][32 + (quad << 3)];
#pragma unroll
            for (int i = 0; i < 2; ++i) {
                O[i][t] = __builtin_amdgcn_mfma_f32_16x16x32_bf16(aP[i][0], b0, O[i][t], 0, 0, 0);
                O[i][t] = __builtin_amdgcn_mfma_f32_16x16x32_bf16(aP[i][1], b1, O[i][t], 0, 0, 0);
            }
        }
    }

    // deferred l reduction (16 lanes of the quad)
#pragma unroll
    for (int i = 0; i < 2; ++i)
#pragma unroll
        for (int r = 0; r < 4; ++r) {
#pragma unroll
            for (int off = 1; off < 16; off <<= 1)
                lsum[i][r] += __shfl_xor(lsum[i][r], off);
            lsum[i][r] = 1.0f / lsum[i][r];
        }

    // epilogue: bf16 ctx [b, s, h*64 + d]
#pragma unroll
    for (int i = 0; i < 2; ++i)
#pragma unroll
        for (int t = 0; t < 4; ++t)
#pragma unroll
            for (int r = 0; r < 4; ++r) {
                const int row = qrow0 + (i << 4) + r;
                ctx[((size_t)b * S_ + row) * D_ + (h << 6) + (t << 4) + lq] =
                    f2bf(O[i][t][r] * lsum[i][r]);
            }
}

// ---------------------------------------------------------------------------
// Workspace layout (u16 units), ~61 MB total (unchanged):
//   [0)              xqb,xkb,xvb : 3*XBSZ  (bf16 X; dead after qkv_gemm)
//   [3*XBSZ)         wqb..wob    : 4*WBSZ  (bf16 W)
//   [3*XBSZ+4*WBSZ)  qw,kw,vw    : 3*QSZ
//   after that       mpk         : MPKB bytes (bit-packed mask)
//   cx aliases xqb (attn writes it after qkv_gemm's last read of xvb).
// ---------------------------------------------------------------------------
extern "C" void kernel_launch(void* const* d_in, const int* in_sizes, int n_in,
                              void* d_out, int out_size, void* d_ws, size_t ws_size,
                              hipStream_t stream)
{
    const float* Q    = (const float*)d_in[0];
    const float* K    = (const float*)d_in[1];
    const float* V    = (const float*)d_in[2];
    const int*   mask = (const int*)d_in[3];
    const float* Wq   = (const float*)d_in[4];
    const float* Wk   = (const float*)d_in[5];
    const float* Wv   = (const float*)d_in[6];
    const float* Wo   = (const float*)d_in[7];
    float* out = (float*)d_out;

    u16* xqb = (u16*)d_ws;
    u16* xkb = xqb + XBSZ;
    u16* xvb = xqb + 2 * XBSZ;
    u16* wqb = xqb + 3 * XBSZ;
    u16* wkb = wqb + WBSZ;
    u16* wvb = wqb + 2 * WBSZ;
    u16* wob = wqb + 3 * WBSZ;
    u16* qw  = wqb + 4 * WBSZ;
    u16* kw  = qw + QSZ;
    u16* vw  = qw + 2 * QSZ;
    u8*  mpk = (u8*)(qw + 3 * QSZ);
    u16* cx  = xqb;                 // alias: X-bf16 region is dead by then

    hipLaunchKernelGGL(cvt7m, dim3(2048), dim3(256), 0, stream,
                       Q, K, V, Wq, Wk, Wv, Wo, mask,
                       xqb, xkb, xvb, wqb, wkb, wvb, wob, mpk);
    hipLaunchKernelGGL(qkv_gemm, dim3(NROW / 128, D_ / 128, 3), dim3(256), 0, stream,
                       xqb, xkb, xvb, wqb, wkb, wvb, qw, kw, vw);
    hipLaunchKernelGGL(attn_mfma8, dim3(S_ / 128, H_, B_), dim3(256), 0, stream,
                       qw, kw, vw, mpk, cx);
    hipLaunchKernelGGL(out_gemm, dim3(NROW / 64, D_ / 64), dim3(256), 0, stream,
                       cx, wob, out);
}